// Round 6
// baseline (437.306 us; speedup 1.0000x reference)
//
#include <hip/hip_runtime.h>

// Dims: x[b=32][i=2048][n=16], W[j=64][i=2048][m=32][n=16], bias[j=64][m=32], out v[b=32][j=64][m=32]
// MFMA shape 32x32x16: M=m(32), N=b(32), K=n(16). fp32 -> bf16 hi/lo split, 3 MFMAs/u-tile.
// A frag: lane l holds W[j,i, m=l&31, n=(l>>5)*8+e]  (e=0..7)
// B frag: lane l holds x[b=l&31, i,  n=(l>>5)*8+e]
// C/D:    lane l, reg r = u_hat[b=l&31][m=(r&3)+8*(r>>2)+4*(l>>5)]   (m74/m101-verified)
// ws: sbuf[32*64*32] (256 KB, atomic s accum) + Zinv[32*2048] (256 KB). ws >= 768 KB known-safe.
constexpr float FEPS = 1e-8f;

typedef __attribute__((ext_vector_type(8)))  short bf16x8;
typedef __attribute__((ext_vector_type(16))) float f32x16;

__device__ __forceinline__ short bf16_rne(float f) {
    unsigned u = __float_as_uint(f);
    return (short)((u + 0x7FFFu + ((u >> 16) & 1u)) >> 16);
}
__device__ __forceinline__ float bf16_val(short h) {
    return __uint_as_float(((unsigned)(unsigned short)h) << 16);
}
__device__ __forceinline__ void cvt8(float4 a, float4 b, bf16x8& hi, bf16x8& lo) {
    float v[8] = {a.x, a.y, a.z, a.w, b.x, b.y, b.z, b.w};
    #pragma unroll
    for (int e = 0; e < 8; ++e) {
        const short hb = bf16_rne(v[e]);
        hi[e] = hb;
        lo[e] = bf16_rne(v[e] - bf16_val(hb));
    }
}
#define MFMA(A, B, C) __builtin_amdgcn_mfma_f32_32x32x16_bf16((A), (B), (C), 0, 0, 0)

// ---------------------------------------------------------------------------
// stats: Zinv[b,i] = 1 / sum_j exp(veff[b,j,:] . u_hat[b,j,i,:])
// grid 256 = 8-i slab; 1024 thr = 16 waves (4/SIMD for latency hiding);
// wave w covers j in {w, w+16, w+32, w+48}, all 8 i. W read exactly once per pass.
__global__ __launch_bounds__(1024, 4)
void stats_pass(const float* __restrict__ W, const float* __restrict__ x,
                const float* __restrict__ veff, float* __restrict__ Zinv)
{
    __shared__ float zred[16][32][9];         // [wave][b][i] (+1 pad)
    const int tid = threadIdx.x;
    const int l = tid & 63, w = tid >> 6;     // w = 0..15
    const int b = l & 31, h = l >> 5;
    const int i0 = blockIdx.x * 8;

    // hoist the 8 x-fragments (b = lane&31, n-half = lane>>5)
    bf16x8 xh[8], xl[8];
    #pragma unroll
    for (int ii = 0; ii < 8; ++ii) {
        const float* xr = x + (((size_t)b << 15) + ((size_t)(i0 + ii) << 4) + (h << 3));
        cvt8(*(const float4*)xr, *(const float4*)(xr + 4), xh[ii], xl[ii]);
    }
    float zacc[8];
    #pragma unroll
    for (int ii = 0; ii < 8; ++ii) zacc[ii] = 0.f;

    #pragma unroll 1
    for (int jt = 0; jt < 4; ++jt) {
        const int j = w + (jt << 4);
        const float* vr = veff + ((((size_t)b << 6) | (size_t)j) << 5) + (h << 2);
        const float4 vq0 = *(const float4*)(vr + 0);
        const float4 vq1 = *(const float4*)(vr + 8);
        const float4 vq2 = *(const float4*)(vr + 16);
        const float4 vq3 = *(const float4*)(vr + 24);
        const float* wrow = W + (((size_t)j << 20) + ((size_t)i0 << 9) + (b << 4) + (h << 3));
        #pragma unroll 2
        for (int ii = 0; ii < 8; ++ii) {
            bf16x8 wh, wl;
            cvt8(*(const float4*)wrow, *(const float4*)(wrow + 4), wh, wl);
            wrow += 512;
            f32x16 u;
            #pragma unroll
            for (int r = 0; r < 16; ++r) u[r] = 0.f;
            u = MFMA(wh, xh[ii], u);
            u = MFMA(wh, xl[ii], u);
            u = MFMA(wl, xh[ii], u);
            float th = 0.f;
            th = fmaf(u[0],  vq0.x, th); th = fmaf(u[1],  vq0.y, th);
            th = fmaf(u[2],  vq0.z, th); th = fmaf(u[3],  vq0.w, th);
            th = fmaf(u[4],  vq1.x, th); th = fmaf(u[5],  vq1.y, th);
            th = fmaf(u[6],  vq1.z, th); th = fmaf(u[7],  vq1.w, th);
            th = fmaf(u[8],  vq2.x, th); th = fmaf(u[9],  vq2.y, th);
            th = fmaf(u[10], vq2.z, th); th = fmaf(u[11], vq2.w, th);
            th = fmaf(u[12], vq3.x, th); th = fmaf(u[13], vq3.y, th);
            th = fmaf(u[14], vq3.z, th); th = fmaf(u[15], vq3.w, th);
            const float t = th + __shfl_xor(th, 32, 64);   // both m-halves
            zacc[ii] += __expf(t);
        }
    }
    if (h == 0) {
        #pragma unroll
        for (int ii = 0; ii < 8; ++ii) zred[w][b][ii] = zacc[ii];
    }
    __syncthreads();
    if (tid < 256) {
        const int bb = tid >> 3, ii = tid & 7;
        float z = 0.f;
        #pragma unroll
        for (int ww = 0; ww < 16; ++ww) z += zred[ww][bb][ii];
        Zinv[((size_t)bb << 11) + i0 + ii] = 1.0f / z;
    }
}

// ---------------------------------------------------------------------------
// accum: s[b,j,:] += sum_i c[b,i,j] * u_hat[b,j,i,:]
// grid 256 = (j<<2)|iq; 1024 thr = 16 waves; wave w owns i in [iq*512 + w*32, +32), all 32 b.
// MODE 0: c = 1/64 (MFMA accumulates across i directly). MODE 1: c = exp(veff.u)*Zinv.
// Cross-wave reduce in LDS, then 1 atomicAdd/thread into sbuf (1024/block, 262K total).
template<int MODE>
__global__ __launch_bounds__(1024, 4)
void accum_pass(const float* __restrict__ W, const float* __restrict__ x,
                const float* __restrict__ veff, const float* __restrict__ Zinv,
                float* __restrict__ sbuf)
{
    __shared__ float sred[16][32][36];        // [wave][b][m] (+4 pad)
    const int tid = threadIdx.x;
    const int l = tid & 63, w = tid >> 6;     // w = 0..15
    const int b = l & 31, h = l >> 5;
    const int j  = blockIdx.x >> 2;
    const int iq = blockIdx.x & 3;
    const int ibase = iq * 512 + w * 32;

    float4 vq0, vq1, vq2, vq3;
    if (MODE) {
        const float* vr = veff + ((((size_t)b << 6) | (size_t)j) << 5) + (h << 2);
        vq0 = *(const float4*)(vr + 0);
        vq1 = *(const float4*)(vr + 8);
        vq2 = *(const float4*)(vr + 16);
        vq3 = *(const float4*)(vr + 24);
    }
    f32x16 accs;
    #pragma unroll
    for (int r = 0; r < 16; ++r) accs[r] = 0.f;

    const float* wrow = W + (((size_t)j << 20) + ((size_t)ibase << 9) + (b << 4) + (h << 3));
    #pragma unroll 2
    for (int ii = 0; ii < 32; ++ii) {
        const int i = ibase + ii;
        const float* xr = x + (((size_t)b << 15) + ((size_t)i << 4) + (h << 3));
        bf16x8 xh, xl, wh, wl;
        cvt8(*(const float4*)xr, *(const float4*)(xr + 4), xh, xl);
        cvt8(*(const float4*)wrow, *(const float4*)(wrow + 4), wh, wl);
        wrow += 512;
        if (MODE == 0) {
            accs = MFMA(wh, xh, accs);
            accs = MFMA(wh, xl, accs);
            accs = MFMA(wl, xh, accs);
        } else {
            f32x16 u;
            #pragma unroll
            for (int r = 0; r < 16; ++r) u[r] = 0.f;
            u = MFMA(wh, xh, u);
            u = MFMA(wh, xl, u);
            u = MFMA(wl, xh, u);
            float th = 0.f;
            th = fmaf(u[0],  vq0.x, th); th = fmaf(u[1],  vq0.y, th);
            th = fmaf(u[2],  vq0.z, th); th = fmaf(u[3],  vq0.w, th);
            th = fmaf(u[4],  vq1.x, th); th = fmaf(u[5],  vq1.y, th);
            th = fmaf(u[6],  vq1.z, th); th = fmaf(u[7],  vq1.w, th);
            th = fmaf(u[8],  vq2.x, th); th = fmaf(u[9],  vq2.y, th);
            th = fmaf(u[10], vq2.z, th); th = fmaf(u[11], vq2.w, th);
            th = fmaf(u[12], vq3.x, th); th = fmaf(u[13], vq3.y, th);
            th = fmaf(u[14], vq3.z, th); th = fmaf(u[15], vq3.w, th);
            const float t = th + __shfl_xor(th, 32, 64);
            const float c = __expf(t) * Zinv[((size_t)b << 11) + i];
            #pragma unroll
            for (int r = 0; r < 16; ++r) accs[r] = fmaf(c, u[r], accs[r]);
        }
    }
    const float scale = (MODE == 0) ? 0.015625f : 1.0f;
    #pragma unroll
    for (int q = 0; q < 4; ++q) {
        *(float4*)&sred[w][b][q * 8 + (h << 2)] =
            make_float4(accs[q*4] * scale, accs[q*4+1] * scale,
                        accs[q*4+2] * scale, accs[q*4+3] * scale);
    }
    __syncthreads();
    {
        const int bb = tid >> 5, mm = tid & 31;
        float s = 0.f;
        #pragma unroll
        for (int ww = 0; ww < 16; ++ww) s += sred[ww][bb][mm];
        atomicAdd(sbuf + ((((size_t)bb << 6) | (size_t)j) << 5) + mm, s);
    }
}

// ---------------------------------------------------------------------------
// squash: v = squash(s + bias) (+ vold); then zero sbuf for the next accum pass
// (each thread zeroes exactly the element it read -> deterministic).
__global__ __launch_bounds__(256)
void squash_pass(float* __restrict__ sbuf, const float* __restrict__ bias,
                 float* __restrict__ vout, const float* __restrict__ vold)
{
    const int tid = threadIdx.x;
    const int m = tid & 31, g = tid >> 5;
    const int pair = blockIdx.x * 8 + g;      // b*64 + j
    const int j = pair & 63;
    const size_t idx = ((size_t)pair << 5) + m;
    float s = sbuf[idx] + bias[(j << 5) + m];
    sbuf[idx] = 0.f;                          // re-arm for next accum
    float n2 = s * s;
    n2 += __shfl_xor(n2, 1, 64);  n2 += __shfl_xor(n2, 2, 64);
    n2 += __shfl_xor(n2, 4, 64);  n2 += __shfl_xor(n2, 8, 64);
    n2 += __shfl_xor(n2, 16, 64);
    float v = s * (n2 / (1.f + n2)) / sqrtf(n2 + FEPS);
    if (vold) v += vold[idx];
    vout[idx] = v;
}

extern "C" void kernel_launch(void* const* d_in, const int* in_sizes, int n_in,
                              void* d_out, int out_size, void* d_ws, size_t ws_size,
                              hipStream_t stream)
{
    const float* x    = (const float*)d_in[0];
    const float* W    = (const float*)d_in[1];
    const float* bias = (const float*)d_in[2];
    float* out  = (float*)d_out;              // running veff lives here
    float* sbuf = (float*)d_ws;               // 65536 floats
    float* Zinv = sbuf + 65536;               // 65536 floats

    // one defensive zero of sbuf (first-call garbage); squash re-arms it afterwards
    hipMemsetAsync(sbuf, 0, 65536 * sizeof(float), stream);

    // it0: c = 1/64 exactly
    accum_pass<0><<<256, 1024, 0, stream>>>(W, x, nullptr, nullptr, sbuf);
    squash_pass<<<256, 256, 0, stream>>>(sbuf, bias, out, nullptr);        // out = v0
    // it1
    stats_pass<<<256, 1024, 0, stream>>>(W, x, out, Zinv);
    accum_pass<1><<<256, 1024, 0, stream>>>(W, x, out, Zinv, sbuf);
    squash_pass<<<256, 256, 0, stream>>>(sbuf, bias, out, out);            // out = v0 + v1
    // it2
    stats_pass<<<256, 1024, 0, stream>>>(W, x, out, Zinv);
    accum_pass<1><<<256, 1024, 0, stream>>>(W, x, out, Zinv, sbuf);
    squash_pass<<<256, 256, 0, stream>>>(sbuf, bias, out, nullptr);        // final v
}

// Round 7
// 310.011 us; speedup vs baseline: 1.4106x; 1.4106x over previous
//
#include <hip/hip_runtime.h>

// Dims: x[b=32][i=2048][n=16], W[j=64][i=2048][m=32][n=16], bias[j=64][m=32], out v[b=32][j=64][m=32]
// MFMA shape 32x32x16: M=m(32), N=b(32), K=n(16). fp32 -> bf16 hi/lo split, 3 MFMAs/u-tile.
// A frag: lane l holds W[j,i, m=l&31, n=(l>>5)*8+e]  (e=0..7)
// B frag: lane l holds x[b=l&31, i,  n=(l>>5)*8+e]
// C/D:    lane l, reg r = u_hat[b=l&31][m=(r&3)+8*(r>>2)+4*(l>>5)]   (m74/m101-verified)
// ws: sbuf[32*64*32] (256 KB, atomic s accum) + Zinv[32*2048] (256 KB). ws >= 768 KB known-safe.
// Grid 512 = 2 blocks/CU (16 waves/CU, 4/SIMD) with 512-thr blocks: TLP without the r6 VGPR cap.
constexpr float FEPS = 1e-8f;

typedef __attribute__((ext_vector_type(8)))  short bf16x8;
typedef __attribute__((ext_vector_type(16))) float f32x16;

__device__ __forceinline__ short bf16_rne(float f) {
    unsigned u = __float_as_uint(f);
    return (short)((u + 0x7FFFu + ((u >> 16) & 1u)) >> 16);
}
__device__ __forceinline__ float bf16_val(short h) {
    return __uint_as_float(((unsigned)(unsigned short)h) << 16);
}
__device__ __forceinline__ void cvt8(float4 a, float4 b, bf16x8& hi, bf16x8& lo) {
    float v[8] = {a.x, a.y, a.z, a.w, b.x, b.y, b.z, b.w};
    #pragma unroll
    for (int e = 0; e < 8; ++e) {
        const short hb = bf16_rne(v[e]);
        hi[e] = hb;
        lo[e] = bf16_rne(v[e] - bf16_val(hb));
    }
}
#define MFMA(A, B, C) __builtin_amdgcn_mfma_f32_32x32x16_bf16((A), (B), (C), 0, 0, 0)

// ---------------------------------------------------------------------------
// stats: Zinv[b,i] = 1 / sum_j exp(veff[b,j,:] . u_hat[b,j,i,:])
// grid 512 = 4-i slab; 512 thr = 8 waves; wave w covers j in {w, w+8, .., w+56}, all 4 i.
// W read exactly once per pass. Z complete in-block.
__global__ __launch_bounds__(512, 2)
void stats_pass(const float* __restrict__ W, const float* __restrict__ x,
                const float* __restrict__ veff, float* __restrict__ Zinv)
{
    __shared__ float zred[8][32][5];          // [wave][b][ii] (+1 pad)
    const int tid = threadIdx.x;
    const int l = tid & 63, w = tid >> 6;     // w = 0..7
    const int b = l & 31, h = l >> 5;
    const int i0 = blockIdx.x * 4;

    // hoist the 4 x-fragments (b = lane&31, n-half = lane>>5): 32 VGPRs
    bf16x8 xh[4], xl[4];
    #pragma unroll
    for (int ii = 0; ii < 4; ++ii) {
        const float* xr = x + (((size_t)b << 15) + ((size_t)(i0 + ii) << 4) + (h << 3));
        cvt8(*(const float4*)xr, *(const float4*)(xr + 4), xh[ii], xl[ii]);
    }
    float zacc[4] = {0.f, 0.f, 0.f, 0.f};

    #pragma unroll 1
    for (int jt = 0; jt < 8; ++jt) {
        const int j = w + (jt << 3);
        const float* vr = veff + ((((size_t)b << 6) | (size_t)j) << 5) + (h << 2);
        const float4 vq0 = *(const float4*)(vr + 0);
        const float4 vq1 = *(const float4*)(vr + 8);
        const float4 vq2 = *(const float4*)(vr + 16);
        const float4 vq3 = *(const float4*)(vr + 24);
        const float* wrow = W + (((size_t)j << 20) + ((size_t)i0 << 9) + (b << 4) + (h << 3));
        #pragma unroll
        for (int ii = 0; ii < 4; ++ii) {
            bf16x8 wh, wl;
            cvt8(*(const float4*)wrow, *(const float4*)(wrow + 4), wh, wl);
            wrow += 512;
            f32x16 u;
            #pragma unroll
            for (int r = 0; r < 16; ++r) u[r] = 0.f;
            u = MFMA(wh, xh[ii], u);
            u = MFMA(wh, xl[ii], u);
            u = MFMA(wl, xh[ii], u);
            float th = 0.f;
            th = fmaf(u[0],  vq0.x, th); th = fmaf(u[1],  vq0.y, th);
            th = fmaf(u[2],  vq0.z, th); th = fmaf(u[3],  vq0.w, th);
            th = fmaf(u[4],  vq1.x, th); th = fmaf(u[5],  vq1.y, th);
            th = fmaf(u[6],  vq1.z, th); th = fmaf(u[7],  vq1.w, th);
            th = fmaf(u[8],  vq2.x, th); th = fmaf(u[9],  vq2.y, th);
            th = fmaf(u[10], vq2.z, th); th = fmaf(u[11], vq2.w, th);
            th = fmaf(u[12], vq3.x, th); th = fmaf(u[13], vq3.y, th);
            th = fmaf(u[14], vq3.z, th); th = fmaf(u[15], vq3.w, th);
            const float t = th + __shfl_xor(th, 32, 64);   // both m-halves
            zacc[ii] += __expf(t);
        }
    }
    if (h == 0) {
        #pragma unroll
        for (int ii = 0; ii < 4; ++ii) zred[w][b][ii] = zacc[ii];
    }
    __syncthreads();
    if (tid < 128) {
        const int bb = tid >> 2, ii = tid & 3;
        float z = 0.f;
        #pragma unroll
        for (int ww = 0; ww < 8; ++ww) z += zred[ww][bb][ii];
        Zinv[((size_t)bb << 11) + i0 + ii] = 1.0f / z;
    }
}

// ---------------------------------------------------------------------------
// accum: s[b,j,:] += sum_i c[b,i,j] * u_hat[b,j,i,:]
// grid 512 = (j<<3)|iq; 512 thr = 8 waves; wave w owns i in [iq*256 + w*32, +32), all 32 b.
// MODE 0: c = 1/64 (MFMA accumulates across i directly). MODE 1: c = exp(veff.u)*Zinv.
// Cross-wave LDS reduce, then 2 atomicAdds/thread into sbuf (1024/block, 524K/pass ~8us).
template<int MODE>
__global__ __launch_bounds__(512, 2)
void accum_pass(const float* __restrict__ W, const float* __restrict__ x,
                const float* __restrict__ veff, const float* __restrict__ Zinv,
                float* __restrict__ sbuf)
{
    __shared__ float sred[8][32][36];         // [wave][b][m] (+4 pad)
    const int tid = threadIdx.x;
    const int l = tid & 63, w = tid >> 6;     // w = 0..7
    const int b = l & 31, h = l >> 5;
    const int j  = blockIdx.x >> 3;
    const int iq = blockIdx.x & 7;
    const int ibase = iq * 256 + w * 32;

    float4 vq0, vq1, vq2, vq3;
    if (MODE) {
        const float* vr = veff + ((((size_t)b << 6) | (size_t)j) << 5) + (h << 2);
        vq0 = *(const float4*)(vr + 0);
        vq1 = *(const float4*)(vr + 8);
        vq2 = *(const float4*)(vr + 16);
        vq3 = *(const float4*)(vr + 24);
    }
    f32x16 accs;
    #pragma unroll
    for (int r = 0; r < 16; ++r) accs[r] = 0.f;

    const float* wrow = W + (((size_t)j << 20) + ((size_t)ibase << 9) + (b << 4) + (h << 3));
    #pragma unroll 2
    for (int ii = 0; ii < 32; ++ii) {
        const int i = ibase + ii;
        const float* xr = x + (((size_t)b << 15) + ((size_t)i << 4) + (h << 3));
        bf16x8 xh, xl, wh, wl;
        cvt8(*(const float4*)xr, *(const float4*)(xr + 4), xh, xl);
        cvt8(*(const float4*)wrow, *(const float4*)(wrow + 4), wh, wl);
        wrow += 512;
        if (MODE == 0) {
            accs = MFMA(wh, xh, accs);
            accs = MFMA(wh, xl, accs);
            accs = MFMA(wl, xh, accs);
        } else {
            f32x16 u;
            #pragma unroll
            for (int r = 0; r < 16; ++r) u[r] = 0.f;
            u = MFMA(wh, xh, u);
            u = MFMA(wh, xl, u);
            u = MFMA(wl, xh, u);
            float th = 0.f;
            th = fmaf(u[0],  vq0.x, th); th = fmaf(u[1],  vq0.y, th);
            th = fmaf(u[2],  vq0.z, th); th = fmaf(u[3],  vq0.w, th);
            th = fmaf(u[4],  vq1.x, th); th = fmaf(u[5],  vq1.y, th);
            th = fmaf(u[6],  vq1.z, th); th = fmaf(u[7],  vq1.w, th);
            th = fmaf(u[8],  vq2.x, th); th = fmaf(u[9],  vq2.y, th);
            th = fmaf(u[10], vq2.z, th); th = fmaf(u[11], vq2.w, th);
            th = fmaf(u[12], vq3.x, th); th = fmaf(u[13], vq3.y, th);
            th = fmaf(u[14], vq3.z, th); th = fmaf(u[15], vq3.w, th);
            const float t = th + __shfl_xor(th, 32, 64);
            const float c = __expf(t) * Zinv[((size_t)b << 11) + i];
            #pragma unroll
            for (int r = 0; r < 16; ++r) accs[r] = fmaf(c, u[r], accs[r]);
        }
    }
    const float scale = (MODE == 0) ? 0.015625f : 1.0f;
    #pragma unroll
    for (int q = 0; q < 4; ++q) {
        *(float4*)&sred[w][b][q * 8 + (h << 2)] =
            make_float4(accs[q*4] * scale, accs[q*4+1] * scale,
                        accs[q*4+2] * scale, accs[q*4+3] * scale);
    }
    __syncthreads();
    #pragma unroll
    for (int k = 0; k < 2; ++k) {
        const int idx = tid * 2 + k;
        const int bb = idx >> 5, mm = idx & 31;
        float s = 0.f;
        #pragma unroll
        for (int ww = 0; ww < 8; ++ww) s += sred[ww][bb][mm];
        atomicAdd(sbuf + ((((size_t)bb << 6) | (size_t)j) << 5) + mm, s);
    }
}

// ---------------------------------------------------------------------------
// squash: v = squash(s + bias) (+ vold); then zero sbuf for the next accum pass
// (each thread zeroes exactly the element it read -> deterministic).
__global__ __launch_bounds__(256)
void squash_pass(float* __restrict__ sbuf, const float* __restrict__ bias,
                 float* __restrict__ vout, const float* __restrict__ vold)
{
    const int tid = threadIdx.x;
    const int m = tid & 31, g = tid >> 5;
    const int pair = blockIdx.x * 8 + g;      // b*64 + j
    const int j = pair & 63;
    const size_t idx = ((size_t)pair << 5) + m;
    float s = sbuf[idx] + bias[(j << 5) + m];
    sbuf[idx] = 0.f;                          // re-arm for next accum
    float n2 = s * s;
    n2 += __shfl_xor(n2, 1, 64);  n2 += __shfl_xor(n2, 2, 64);
    n2 += __shfl_xor(n2, 4, 64);  n2 += __shfl_xor(n2, 8, 64);
    n2 += __shfl_xor(n2, 16, 64);
    float v = s * (n2 / (1.f + n2)) / sqrtf(n2 + FEPS);
    if (vold) v += vold[idx];
    vout[idx] = v;
}

extern "C" void kernel_launch(void* const* d_in, const int* in_sizes, int n_in,
                              void* d_out, int out_size, void* d_ws, size_t ws_size,
                              hipStream_t stream)
{
    const float* x    = (const float*)d_in[0];
    const float* W    = (const float*)d_in[1];
    const float* bias = (const float*)d_in[2];
    float* out  = (float*)d_out;              // running veff lives here
    float* sbuf = (float*)d_ws;               // 65536 floats
    float* Zinv = sbuf + 65536;               // 65536 floats

    // one defensive zero of sbuf (first-call garbage); squash re-arms it afterwards
    hipMemsetAsync(sbuf, 0, 65536 * sizeof(float), stream);

    // it0: c = 1/64 exactly
    accum_pass<0><<<512, 512, 0, stream>>>(W, x, nullptr, nullptr, sbuf);
    squash_pass<<<256, 256, 0, stream>>>(sbuf, bias, out, nullptr);        // out = v0
    // it1
    stats_pass<<<512, 512, 0, stream>>>(W, x, out, Zinv);
    accum_pass<1><<<512, 512, 0, stream>>>(W, x, out, Zinv, sbuf);
    squash_pass<<<256, 256, 0, stream>>>(sbuf, bias, out, out);            // out = v0 + v1
    // it2
    stats_pass<<<512, 512, 0, stream>>>(W, x, out, Zinv);
    accum_pass<1><<<512, 512, 0, stream>>>(W, x, out, Zinv, sbuf);
    squash_pass<<<256, 256, 0, stream>>>(sbuf, bias, out, nullptr);        // final v
}